// Round 1
// 360.252 us; speedup vs baseline: 1.1045x; 1.1045x over previous
//
#include <hip/hip_runtime.h>

#define N_NODES 100000
#define IN_DIM 256
#define OUT_DIM 128
#define N_EDGES 3200000

#define NB 1563            // ceil(100000 / 64) buckets of 64 dst nodes
#define CAP 2560           // bucket capacity; mean 2048, sigma ~45 -> 11 sigma slack
#define PTILE 6400         // edges per partition block
#define PBLK 500           // 500 * 6400 = 3.2M exactly
#define GBLK 782           // ceil(100000 / 128) gemm blocks (8 waves x 16 rows)

typedef __attribute__((ext_vector_type(8))) short short8;   // 8 bf16 (4 VGPRs)
typedef __attribute__((ext_vector_type(4))) float float4v;  // 4 f32 acc

// round-nearest-even f32 -> bf16 bits
__device__ __forceinline__ unsigned short f2bf(float f) {
    union { float f; unsigned int u; } v; v.f = f;
    unsigned int r = v.u + 0x7FFF + ((v.u >> 16) & 1);
    return (unsigned short)(r >> 16);
}

// ---------------------------------------------------------------------------
// Kernel 0 (setup): blocks 0-15 swizzle W into bf16 MFMA B-fragment-major
// order; blocks 16-22 zero the bucket cursors.
// ---------------------------------------------------------------------------
__global__ __launch_bounds__(256) void setup_kernel(const float* __restrict__ W,
                                                    unsigned short* __restrict__ Wf,
                                                    int* __restrict__ cursor) {
    if (blockIdx.x < 16) {
        const int f = blockIdx.x * 256 + threadIdx.x;      // < 4096
        const int lane = f & 63;
        const int qc = f >> 6;
        const int q = qc >> 3, ct = qc & 7;
        const int n = ct * 16 + (lane & 15);
        const int k0 = q * 32 + (lane >> 4) * 8;
        unsigned int o[4];
#pragma unroll
        for (int jj = 0; jj < 4; ++jj) {
            const unsigned short lo = f2bf(W[(k0 + 2 * jj) * OUT_DIM + n]);
            const unsigned short hi = f2bf(W[(k0 + 2 * jj + 1) * OUT_DIM + n]);
            o[jj] = (unsigned)lo | ((unsigned)hi << 16);
        }
        ((uint4*)Wf)[f] = make_uint4(o[0], o[1], o[2], o[3]);
    } else {
        const int i = (blockIdx.x - 16) * 256 + threadIdx.x;
        if (i < NB) cursor[i] = 0;
    }
}

// ---------------------------------------------------------------------------
// Kernel 1 (fused): partition + gemm, INTERLEAVED in dispatch order so each
// CU co-hosts latency-bound partition blocks and MFMA-bound gemm blocks
// (blocks 0..999: even=partition pid=bx>>1, odd=gemm gid=bx>>1;
//  blocks 1000..1281: gemm gid=bx-500).
// Partition is now SINGLE-pass: the pass-1 LDS atomicAdd already yields the
// per-bucket rank; (bucket,rank,dst&63) packed in a register, src/vals
// prefetched into registers alongside (their latency hides under the global
// cursor-atomic phase). 4 phases instead of 6: one dst read pass, one LDS
// atomic pass, one histogram zeroing and one barrier eliminated.
// ---------------------------------------------------------------------------
__global__ __launch_bounds__(512, 4) void fused_kernel(const float* __restrict__ X,
                                                       const unsigned short* __restrict__ Wf,
                                                       unsigned short* __restrict__ hb,
                                                       const int* __restrict__ src,
                                                       const int* __restrict__ dst,
                                                       const float* __restrict__ vals,
                                                       int* __restrict__ cursor,
                                                       int2* __restrict__ pairs) {
    __shared__ int smem[8192];                         // 32 KB union
    const int tid = threadIdx.x;
    const int bx = blockIdx.x;
    const bool is_part = (bx < 1000) && ((bx & 1) == 0);

    if (is_part) {
        // ================= partition branch =================
        int* lhist = smem;
        int* lbase = smem + NB;
        const int pid = bx >> 1;                       // 0..499
        const int base = pid * PTILE;

        for (int i = tid; i < NB; i += 512) lhist[i] = 0;
        __syncthreads();

        // pass 1: histogram + rank in ONE pass; prefetch src/vals to regs.
        // pk = b(11b)<<19 | r(13b)<<6 | d&63 ; -1 = inactive lane
        int   pk[13];
        int   sv[13];
        float vv[13];
#pragma unroll
        for (int k = 0; k < 13; ++k) {                 // 13*512 >= 6400
            const int e = base + tid + k * 512;
            pk[k] = -1;
            if (tid + k * 512 < PTILE) {
                const int d = dst[e];
                const int b = d >> 6;
                const int r = atomicAdd(&lhist[b], 1); // rank AND count
                pk[k] = (b << 19) | (r << 6) | (d & 63);
                sv[k] = src[e];
                vv[k] = vals[e];
            }
        }
        __syncthreads();

        // per-block bucket bases via global cursor (contended, latency-bound;
        // src/vals loads above are still in flight underneath this)
        for (int i = tid; i < NB; i += 512) {
            const int c = lhist[i];
            if (c) lbase[i] = atomicAdd(&cursor[i], c);
        }
        __syncthreads();

        // scatter phase: pure stores, no re-reads, no atomics
#pragma unroll
        for (int k = 0; k < 13; ++k) {
            if (pk[k] >= 0) {
                const int b = pk[k] >> 19;
                const int r = (pk[k] >> 6) & 0x1FFF;
                const int pos = lbase[b] + r;
                if (pos < CAP)                          // 11-sigma overflow guard
                    pairs[(long)b * CAP + pos] =
                        make_int2(sv[k] | ((pk[k] & 63) << 20), __float_as_int(vv[k]));
            }
        }
    } else {
        // ================= gemm branch =================
        const int gid = (bx < 1000) ? (bx >> 1) : (bx - 500);   // 0..781
        const int wid = tid >> 6;                      // 8 waves x 16 rows
        const int lane = tid & 63;
        const int m = lane & 15;
        const int quad = lane >> 4;
        const int row0 = gid * 128 + wid * 16;

        // load all 8 A fragments (A[m=lane&15][k=quad*8+j], verified layout)
        const int rl = min(row0 + m, N_NODES - 1);     // clamp tail reads
        const float* xr = X + (long)rl * IN_DIM + quad * 8;
        short8 afrag[8];
#pragma unroll
        for (int q = 0; q < 8; ++q) {
            const float4 xa = *(const float4*)(xr + q * 32);
            const float4 xb = *(const float4*)(xr + q * 32 + 4);
            short8 f;
            f[0] = (short)f2bf(xa.x); f[1] = (short)f2bf(xa.y);
            f[2] = (short)f2bf(xa.z); f[3] = (short)f2bf(xa.w);
            f[4] = (short)f2bf(xb.x); f[5] = (short)f2bf(xb.y);
            f[6] = (short)f2bf(xb.z); f[7] = (short)f2bf(xb.w);
            afrag[q] = f;
        }

        // per-wave private 4 KB store stage (in-order DS: no barrier needed)
        unsigned short* stage = (unsigned short*)smem + wid * 2048;
        const short8* wfrag = (const short8*)Wf;
#pragma unroll 1
        for (int ct = 0; ct < 8; ++ct) {
            float4v acc = {0.f, 0.f, 0.f, 0.f};
#pragma unroll
            for (int q = 0; q < 8; ++q) {
                const short8 bfr = wfrag[(q * 8 + ct) * 64 + lane];
                acc = __builtin_amdgcn_mfma_f32_16x16x32_bf16(afrag[q], bfr, acc, 0, 0, 0);
            }
            // C/D: col=lane&15, row=quad*4+reg (m89-verified)
#pragma unroll
            for (int r = 0; r < 4; ++r)
                stage[(quad * 4 + r) * 128 + ct * 16 + m] = f2bf(acc[r]);
        }

        // coalesced writeback: 4 x (ds_read_b128 + dwordx4), 1 KB contiguous
#pragma unroll
        for (int j = 0; j < 4; ++j) {
            const uint4 vdata = *(const uint4*)(stage + j * 512 + lane * 8);
            const int row_r = row0 + j * 4 + quad;
            if (row_r < N_NODES)
                *(uint4*)(hb + (long)row_r * OUT_DIM + m * 8) = vdata;
        }
    }
}

// ---------------------------------------------------------------------------
// Kernel 2: bucket gather-reduce (counting-sort to LDS + register acc).
// Phase 2 main loop deepened to 16 independent gathers per batch (4 KB
// outstanding per wave) against L2/L3 latency; 8-deep and scalar tails.
// ---------------------------------------------------------------------------
__global__ __launch_bounds__(256) void gather_kernel(const int* __restrict__ cursor,
                                                     const int2* __restrict__ pairs,
                                                     const unsigned short* __restrict__ hb,
                                                     const float* __restrict__ bias,
                                                     float* __restrict__ out) {
    __shared__ int2 lp[CAP];                           // 20,480 B sorted pairs
    __shared__ int rcnt[64];
    __shared__ int rbase[64];
    const int blk = blockIdx.x;
    const int tid = threadIdx.x;
    const int wid = tid >> 6;
    const int lane = tid & 63;
    const int c = lane * 2;                            // cols {c, c+1}

    const long beg = (long)blk * CAP;
    const int cnt = min(cursor[blk], CAP);

    if (tid < 64) rcnt[tid] = 0;
    __syncthreads();

    // phase 1a: rank (CAP = 10 * 256 exactly)
    int2 sp[10];
    int  sr[10];
#pragma unroll
    for (int k = 0; k < 10; ++k) {
        const int i = tid + k * 256;
        sr[k] = -1;
        if (i < cnt) {
            const int2 p = pairs[beg + i];
            const int r = (p.x >> 20) & 63;
            const int rk = atomicAdd(&rcnt[r], 1);     // native LDS int atomic
            sp[k] = p;
            sr[k] = (r << 13) | rk;
        }
    }
    __syncthreads();

    // phase 1b: exclusive scan of 64 row counts (wave 0, shfl scan)
    if (wid == 0) {
        const int v = rcnt[lane];
        int incl = v;
#pragma unroll
        for (int off = 1; off < 64; off <<= 1) {
            const int t = __shfl_up(incl, off);
            if (lane >= off) incl += t;
        }
        rbase[lane] = incl - v;
    }
    __syncthreads();

    // phase 1c: scatter into sorted LDS array
#pragma unroll
    for (int k = 0; k < 10; ++k) {
        if (sr[k] >= 0)
            lp[rbase[sr[k] >> 13] + (sr[k] & 0x1FFF)] = sp[k];
    }
    __syncthreads();

    // phase 2: per-row register accumulation, 16-deep MLP main loop
    const float2 bb = *(const float2*)(bias + c);
#pragma unroll 1
    for (int rr = 0; rr < 16; ++rr) {
        const int r = wid * 16 + rr;
        const int node = blk * 64 + r;
        if (node >= N_NODES) break;
        const int rb = rbase[r];
        const int re = rb + rcnt[r];

        float2 acc[8];
#pragma unroll
        for (int t = 0; t < 8; ++t) acc[t] = make_float2(0.f, 0.f);

        int j = rb;
        for (; j + 15 < re; j += 16) {
            int2 p[16];
            unsigned u[16];
#pragma unroll
            for (int t = 0; t < 16; ++t) p[t] = lp[j + t];
#pragma unroll
            for (int t = 0; t < 16; ++t)
                u[t] = *(const unsigned*)(hb + (long)(p[t].x & 0xFFFFF) * OUT_DIM + c);
#pragma unroll
            for (int t = 0; t < 16; ++t) {
                const float v = __int_as_float(p[t].y);
                acc[t & 7].x += v * __uint_as_float(u[t] << 16);
                acc[t & 7].y += v * __uint_as_float(u[t] & 0xFFFF0000u);
            }
        }
        for (; j + 7 < re; j += 8) {
            int2 p[8];
            unsigned u[8];
#pragma unroll
            for (int t = 0; t < 8; ++t) p[t] = lp[j + t];
#pragma unroll
            for (int t = 0; t < 8; ++t)
                u[t] = *(const unsigned*)(hb + (long)(p[t].x & 0xFFFFF) * OUT_DIM + c);
#pragma unroll
            for (int t = 0; t < 8; ++t) {
                const float v = __int_as_float(p[t].y);
                acc[t].x += v * __uint_as_float(u[t] << 16);
                acc[t].y += v * __uint_as_float(u[t] & 0xFFFF0000u);
            }
        }
        for (; j < re; ++j) {
            const int2 p0 = lp[j];
            const unsigned u0 = *(const unsigned*)(hb + (long)(p0.x & 0xFFFFF) * OUT_DIM + c);
            const float v0 = __int_as_float(p0.y);
            acc[0].x += v0 * __uint_as_float(u0 << 16);
            acc[0].y += v0 * __uint_as_float(u0 & 0xFFFF0000u);
        }
        float2 o;
        o.x = bb.x + ((acc[0].x + acc[1].x) + (acc[2].x + acc[3].x))
                   + ((acc[4].x + acc[5].x) + (acc[6].x + acc[7].x));
        o.y = bb.y + ((acc[0].y + acc[1].y) + (acc[2].y + acc[3].y))
                   + ((acc[4].y + acc[5].y) + (acc[6].y + acc[7].y));
        *(float2*)(out + (long)node * OUT_DIM + c) = o;
    }
}

// ---------------------------------------------------------------------------
extern "C" void kernel_launch(void* const* d_in, const int* in_sizes, int n_in,
                              void* d_out, int out_size, void* d_ws, size_t ws_size,
                              hipStream_t stream) {
    const float* X     = (const float*)d_in[0];
    const int*   esrc  = (const int*)d_in[1];
    const int*   edst  = (const int*)d_in[2];
    const float* evals = (const float*)d_in[3];
    const float* W     = (const float*)d_in[4];
    const float* b     = (const float*)d_in[5];
    float* out = (float*)d_out;

    // workspace layout (bytes)
    char* ws = (char*)d_ws;
    unsigned short* hb = (unsigned short*)(ws);                  // 25,600,000
    int2* pairs        = (int2*)(ws + 25600000);                 // 32,010,240
    int*  cursor       = (int*) (ws + 25600000 + 32010240);      //      6,252
    unsigned short* Wf = (unsigned short*)(ws + 57616496);       //     65,536

    setup_kernel<<<dim3(23), dim3(256), 0, stream>>>(W, Wf, cursor);
    fused_kernel<<<dim3(PBLK + GBLK), dim3(512), 0, stream>>>(X, Wf, hb,
                                                              esrc, edst, evals,
                                                              cursor, pairs);
    gather_kernel<<<dim3(NB), dim3(256), 0, stream>>>(cursor, pairs, hb, b, out);
}